// Round 8
// baseline (227.503 us; speedup 1.0000x reference)
//
#include <hip/hip_runtime.h>
#include <hip/hip_bf16.h>

// Problem constants
#define BB 2
#define SS 2048
#define DD 1024
#define HH 16
#define HD 64
#define MM (BB*SS)   // 4096

typedef __attribute__((ext_vector_type(8))) short bf16x8;
typedef __attribute__((ext_vector_type(4))) float f32x4;

static __device__ inline unsigned short f2bf(float x) {
    unsigned int u = __float_as_uint(x);
    unsigned int r = (u + 0x7fffu + ((u >> 16) & 1u)) >> 16;
    return (unsigned short)r;
}

// packed f32x2 -> bf16x2 via v_cvt_pk_bf16_f32 (RNE, bit-identical to f2bf)
static __device__ inline unsigned pack2bf(float lo, float hi) {
    union { __hip_bfloat162 h; unsigned u; } c;
    c.h = __float22bfloat162_rn(make_float2(lo, hi));
    return c.u;
}

static __device__ inline f32x4 mfma16(bf16x8 a, bf16x8 b, f32x4 c) {
    return __builtin_amdgcn_mfma_f32_16x16x32_bf16(a, b, c, 0, 0, 0);
}

// raw v_exp_f32 (2^x)
static __device__ inline float fast_exp2(float x) {
    return __builtin_amdgcn_exp2f(x);
}

// async global->LDS 16B per lane: LDS dest = wave-uniform base + lane*16
typedef __attribute__((address_space(3))) unsigned int lds_u32;
typedef const __attribute__((address_space(1))) unsigned int glb_u32;
static __device__ inline void async_ld16(const void* g, void* l) {
    __builtin_amdgcn_global_load_lds((glb_u32*)g, (lds_u32*)l, 16, 0, 0);
}

// ---------------- prep (weights only): transpose+convert [R][C]fp32 -> [C][R]bf16
struct PrepArgs {
    const float* wsrc[4];
    unsigned short* wdst[4];
};
__global__ __launch_bounds__(256) void prep_inputs(PrepArgs args) {
    __shared__ float tile[32][33];
    const int z = blockIdx.z;
    const int t = threadIdx.x;
    const float* in = args.wsrc[z];
    unsigned short* out = args.wdst[z];
    const int c0 = blockIdx.x * 32, r0 = blockIdx.y * 32;
    {
        const int xf = (t & 7) * 4, yf = t >> 3;     // load float4 per thread
        float4 v = *(const float4*)(in + (size_t)(r0 + yf) * DD + c0 + xf);
        tile[yf][xf + 0] = v.x;
        tile[yf][xf + 1] = v.y;
        tile[yf][xf + 2] = v.z;
        tile[yf][xf + 3] = v.w;
    }
    __syncthreads();
    {
        const int x8 = t & 7, y8 = t >> 3;           // one uint2 (4 bf16) per thread
        uint2 w;
        w.x = pack2bf(tile[x8 * 4 + 0][y8], tile[x8 * 4 + 1][y8]);
        w.y = pack2bf(tile[x8 * 4 + 2][y8], tile[x8 * 4 + 3][y8]);
        *(uint2*)(out + (size_t)(c0 + y8) * DD + r0 + x8 * 4) = w;
    }
}

struct QKVArgs {
    const float* Af[3];           // raw fp32 activations (query/key/value)
    const unsigned short* Bt[3];
    const float* bias[3];
    unsigned short* C[3];
};

// Q scale folds 1/sqrt(HD) AND log2(e) so flash can use exp2 directly.
#define QSCALE 0.1803368801111204f

// ---------------- QKV GEMM: 256x256, BK=64, 2-buf, fused fp32->bf16 A-staging ------
// Round-8 change: XCD-chunked bijective block swizzle (T1). The r7 counters
// showed FETCH 104.5MB vs ~54MB ideal: blocks sharing an A-panel (same y,
// x=0..3) are CONSECUTIVE in linear order -> round-robin to 4 different XCDs
// -> A fetched 4x. Swizzle gives each XCD a contiguous chunk of 24 tiles
// (192 blocks / 8 XCDs), so A-panel sharers co-locate on one XCD's L2.
// Grid launched 1-D (192 blocks); tile coords decoded from swizzled id.
#define NKT 16   // K / 64

__global__ __launch_bounds__(512, 2) void gemm_qkv(QKVArgs args) {
    __shared__ alignas(16) unsigned short AS[2][256 * 64];
    __shared__ alignas(16) unsigned short BS[2][256 * 64];
    // ---- XCD swizzle: 192 blocks = 8 XCDs x 24-tile chunks (bijective: 192%8==0)
    const int lin = blockIdx.x;
    const int swz = (lin & 7) * 24 + (lin >> 3);
    const int z  = swz >> 6;            // 0..2
    const int by = (swz >> 2) & 15;     // 0..15
    const int bx = swz & 3;             // 0..3
    const float scale = (z == 0) ? QSCALE : 1.0f;
    const float* __restrict__ Af = args.Af[z];
    const unsigned short* __restrict__ Bt = args.Bt[z];
    const float* __restrict__ bias = args.bias[z];
    unsigned short* __restrict__ C = args.C[z];
    const int K = DD, N = DD;
    const int t = threadIdx.x;
    const int lane = t & 63, wave = t >> 6;
    const int quad = lane >> 4, l15 = lane & 15;
    const int wm = wave & 1, wn = wave >> 1;    // 2 M-waves x 4 N-waves
    const int m0 = by * 256, n0 = bx * 256;

    // B staging (bf16, global_load_lds): row t>>3 per 128-row group, slot t&7,
    // source slot pre-swizzled so linear LDS dest + swizzled ds_read match.
    const int srow = t >> 3;                     // 0..63
    const int cslot = (t & 7) ^ (srow & 7);
    const unsigned short* gB = Bt + (size_t)(n0 + srow) * K + cslot * 8;
    const int dstoff = srow * 64 + (t & 7) * 8;  // bytes = t*16 within group

    auto stageB = [&](int tl, int h) {           // h: 0 = rows 0..127, 1 = 128..255
        unsigned short* d = &BS[tl & 1][h * 128 * 64 + dstoff];
        const unsigned short* s = gB + (size_t)(h * 128) * K + (size_t)tl * 64;
        async_ld16(s, d);
        async_ld16(s + (size_t)64 * K, d + 64 * 64);
    };

    // A staging (fp32 -> bf16 reg-staged): thread covers row h*64 + (t>>3),
    // 16B-dst slot t&7; fp32 source col-group (slot ^ (row&7)) -> LDS[row][slot]
    // holds global slot^(row&7), matching the ds_read swizzle below.
    const int ar_ = t >> 3, as_ = t & 7;
    const int sw = as_ ^ (ar_ & 7);
    const float* gA0 = Af + (size_t)(m0 + 0 * 64 + ar_) * K + sw * 8;
    const float* gA1 = Af + (size_t)(m0 + 1 * 64 + ar_) * K + sw * 8;
    const float* gA2 = Af + (size_t)(m0 + 2 * 64 + ar_) * K + sw * 8;
    const float* gA3 = Af + (size_t)(m0 + 3 * 64 + ar_) * K + sw * 8;

    float4 fA0[8], fA1[8];
#define ISSUE_A(buf_, tl_)                                                    \
    {                                                                         \
        const size_t ko_ = (size_t)(tl_) * 64;                                \
        buf_[0] = *(const float4*)(gA0 + ko_);                                \
        buf_[1] = *(const float4*)(gA0 + ko_ + 4);                            \
        buf_[2] = *(const float4*)(gA1 + ko_);                                \
        buf_[3] = *(const float4*)(gA1 + ko_ + 4);                            \
        buf_[4] = *(const float4*)(gA2 + ko_);                                \
        buf_[5] = *(const float4*)(gA2 + ko_ + 4);                            \
        buf_[6] = *(const float4*)(gA3 + ko_);                                \
        buf_[7] = *(const float4*)(gA3 + ko_ + 4);                            \
    }
#define CVT_WRITE_A(buf_, tl_)                                                \
    {                                                                         \
        _Pragma("unroll")                                                     \
        for (int h = 0; h < 4; h++) {                                         \
            uint4 w_;                                                         \
            w_.x = pack2bf(buf_[h * 2].x, buf_[h * 2].y);                     \
            w_.y = pack2bf(buf_[h * 2].z, buf_[h * 2].w);                     \
            w_.z = pack2bf(buf_[h * 2 + 1].x, buf_[h * 2 + 1].y);             \
            w_.w = pack2bf(buf_[h * 2 + 1].z, buf_[h * 2 + 1].w);             \
            *(uint4*)&AS[(tl_) & 1][(h * 64 + ar_) * 64 + as_ * 8] = w_;      \
        }                                                                     \
    }

    // prologue: a0 regs (8), B0 glds (4), a1 regs (8)
    ISSUE_A(fA0, 0);
    stageB(0, 0); stageB(0, 1);
    ISSUE_A(fA1, 1);
    asm volatile("s_waitcnt vmcnt(8)" ::: "memory");   // a0 + B0 done, a1 in flight
    CVT_WRITE_A(fA0, 0);
    asm volatile("s_waitcnt lgkmcnt(0)" ::: "memory");
    __builtin_amdgcn_s_barrier();

    f32x4 acc[8][4];
#pragma unroll
    for (int i = 0; i < 8; i++)
#pragma unroll
        for (int j = 0; j < 4; j++) acc[i][j] = (f32x4){0.f, 0.f, 0.f, 0.f};

#pragma unroll 2
    for (int kt = 0; kt < NKT; ++kt) {
        // top: drain B(kt) glds (a(kt+1) regs stay in flight) + last A ds_writes
        if (kt > 0) {
            if (kt < NKT - 1) asm volatile("s_waitcnt vmcnt(8) lgkmcnt(0)" ::: "memory");
            else              asm volatile("s_waitcnt vmcnt(0) lgkmcnt(0)" ::: "memory");
            __builtin_amdgcn_s_barrier();
        }

        const unsigned short* Ab = AS[kt & 1];
        const unsigned short* Bb = BS[kt & 1];
        bf16x8 af[4][2], bf[4][2];

        // ---- P0: af rows 0..63 of wave-half + bf cols 0..31; issue B(kt+1)
#pragma unroll
        for (int i = 0; i < 4; i++) {
            const int row = wm * 128 + i * 16 + l15;
#pragma unroll
            for (int kk = 0; kk < 2; kk++)
                af[i][kk] = *(const bf16x8*)&Ab[row * 64 + ((kk * 4 + quad) ^ (l15 & 7)) * 8];
        }
#pragma unroll
        for (int j = 0; j < 2; j++) {
            const int row = wn * 64 + j * 16 + l15;
#pragma unroll
            for (int kk = 0; kk < 2; kk++)
                bf[j][kk] = *(const bf16x8*)&Bb[row * 64 + ((kk * 4 + quad) ^ (l15 & 7)) * 8];
        }
        if (kt + 1 < NKT) { stageB(kt + 1, 0); stageB(kt + 1, 1); }
        __builtin_amdgcn_s_barrier();
        __builtin_amdgcn_s_setprio(1);
#pragma unroll
        for (int i = 0; i < 4; i++)
#pragma unroll
            for (int j = 0; j < 2; j++) {
                acc[i][j] = mfma16(af[i][0], bf[j][0], acc[i][j]);
                acc[i][j] = mfma16(af[i][1], bf[j][1], acc[i][j]);
            }
        __builtin_amdgcn_s_setprio(0);
        __builtin_amdgcn_s_barrier();

        // ---- P1: bf cols 32..63
#pragma unroll
        for (int j = 2; j < 4; j++) {
            const int row = wn * 64 + j * 16 + l15;
#pragma unroll
            for (int kk = 0; kk < 2; kk++)
                bf[j][kk] = *(const bf16x8*)&Bb[row * 64 + ((kk * 4 + quad) ^ (l15 & 7)) * 8];
        }
        __builtin_amdgcn_s_barrier();
        __builtin_amdgcn_s_setprio(1);
#pragma unroll
        for (int i = 0; i < 4; i++)
#pragma unroll
            for (int j = 2; j < 4; j++) {
                acc[i][j] = mfma16(af[i][0], bf[j][0], acc[i][j]);
                acc[i][j] = mfma16(af[i][1], bf[j][1], acc[i][j]);
            }
        __builtin_amdgcn_s_setprio(0);
        __builtin_amdgcn_s_barrier();

        // ---- P2: af rows 64..127 of wave-half (reuse regs)
#pragma unroll
        for (int i = 0; i < 4; i++) {
            const int row = wm * 128 + 64 + i * 16 + l15;
#pragma unroll
            for (int kk = 0; kk < 2; kk++)
                af[i][kk] = *(const bf16x8*)&Ab[row * 64 + ((kk * 4 + quad) ^ (l15 & 7)) * 8];
        }
        __builtin_amdgcn_s_barrier();
        __builtin_amdgcn_s_setprio(1);
#pragma unroll
        for (int i = 0; i < 4; i++)
#pragma unroll
            for (int j = 0; j < 2; j++) {
                acc[4 + i][j] = mfma16(af[i][0], bf[j][0], acc[4 + i][j]);
                acc[4 + i][j] = mfma16(af[i][1], bf[j][1], acc[4 + i][j]);
            }
        __builtin_amdgcn_s_setprio(0);
        __builtin_amdgcn_s_barrier();

        // ---- P3: cvt+write A(kt+1) into AS[(kt+1)&1] (other buffer — race-free),
        //      then issue A(kt+2) regs (WAR handled by compiler waitcnts).
        if (kt + 1 < NKT) {
            CVT_WRITE_A(fA1, kt + 1);
            if (kt + 2 < NKT) ISSUE_A(fA1, kt + 2);
        }
        __builtin_amdgcn_s_barrier();
        __builtin_amdgcn_s_setprio(1);
#pragma unroll
        for (int i = 0; i < 4; i++)
#pragma unroll
            for (int j = 2; j < 4; j++) {
                acc[4 + i][j] = mfma16(af[i][0], bf[j][0], acc[4 + i][j]);
                acc[4 + i][j] = mfma16(af[i][1], bf[j][1], acc[4 + i][j]);
            }
        __builtin_amdgcn_s_setprio(0);
        // next K-tile starts with waitcnt + barrier
    }

    if (z == 2) {
        // write C^T into [B][N][S]: token m = b*SS+s, dim col -> dst[b][col][s]
#pragma unroll
        for (int j = 0; j < 4; j++) {
            int col = n0 + wn * 64 + j * 16 + l15;
            float bv = bias[col];
#pragma unroll
            for (int i = 0; i < 8; i++) {
                int rowb = m0 + wm * 128 + i * 16 + quad * 4;
                int b = rowb >> 11, s = rowb & (SS - 1);
                uint2 w;
                w.x = pack2bf(acc[i][j][0] + bv, acc[i][j][1] + bv);
                w.y = pack2bf(acc[i][j][2] + bv, acc[i][j][3] + bv);
                *(uint2*)(C + (size_t)b * DD * SS + (size_t)col * SS + s) = w;
            }
        }
    } else {
#pragma unroll
        for (int j = 0; j < 4; j++) {
            int col = n0 + wn * 64 + j * 16 + l15;
            float bv = bias[col];
#pragma unroll
            for (int i = 0; i < 8; i++) {
                int rowb = m0 + wm * 128 + i * 16 + quad * 4;
#pragma unroll
                for (int rr = 0; rr < 4; rr++) {
                    float v = (acc[i][j][rr] + bv) * scale;
                    C[(size_t)(rowb + rr) * N + col] = f2bf(v);
                }
            }
        }
    }
#undef ISSUE_A
#undef CVT_WRITE_A
}

// ---------------- output projection: pipelined 128x128, BK=64, 2-buf ---------------
// Round-8: + XCD-chunked swizzle (256 blocks = 8 x 32; per XCD 4 row-panels +
// Wo fully L2-resident).
#define ONKT 16   // K / 64

__global__ __launch_bounds__(256, 2) void gemm_out(const unsigned short* __restrict__ A,
                                                   const unsigned short* __restrict__ Bt,
                                                   const float* __restrict__ bias,
                                                   float* __restrict__ C) {
    __shared__ alignas(16) unsigned short AS[2][128 * 64];
    __shared__ alignas(16) unsigned short BS[2][128 * 64];
    const int t = threadIdx.x;
    const int lane = t & 63, wave = t >> 6;
    const int quad = lane >> 4, l15 = lane & 15;
    const int wm = wave & 1, wn = wave >> 1;    // 2 M-waves x 2 N-waves
    // XCD swizzle: 256 blocks = 8 XCDs x 32 (bijective)
    const int lin = blockIdx.x;
    const int swz = (lin & 7) * 32 + (lin >> 3);
    const int bx = swz & 7, by = swz >> 3;
    const int m0 = by * 128, n0 = bx * 128;
    const int K = DD, N = DD;

    const int srow = t >> 3;                     // 0..31
    const int cslot = (t & 7) ^ (srow & 7);
    const unsigned short* gA = A + (size_t)(m0 + srow) * K + cslot * 8;
    const unsigned short* gB = Bt + (size_t)(n0 + srow) * K + cslot * 8;
    const int dstoff = srow * 64 + (t & 7) * 8;

    auto stageA = [&](int tl) {
        unsigned short* d = &AS[tl & 1][dstoff];
        const unsigned short* s = gA + (size_t)tl * 64;
#pragma unroll
        for (int r = 0; r < 4; r++)
            async_ld16(s + (size_t)(r * 32) * K, d + r * 32 * 64);
    };
    auto stageB = [&](int tl) {
        unsigned short* d = &BS[tl & 1][dstoff];
        const unsigned short* s = gB + (size_t)tl * 64;
#pragma unroll
        for (int r = 0; r < 4; r++)
            async_ld16(s + (size_t)(r * 32) * K, d + r * 32 * 64);
    };

    stageA(0); stageB(0); stageA(1);

    f32x4 acc[4][4];
#pragma unroll
    for (int i = 0; i < 4; i++)
#pragma unroll
        for (int j = 0; j < 4; j++) acc[i][j] = (f32x4){0.f, 0.f, 0.f, 0.f};

#pragma unroll 2
    for (int kt = 0; kt < ONKT; ++kt) {
        if (kt < ONKT - 1) asm volatile("s_waitcnt vmcnt(4)" ::: "memory");
        else               asm volatile("s_waitcnt vmcnt(0)" ::: "memory");
        __builtin_amdgcn_s_barrier();

        const unsigned short* Ab = AS[kt & 1];
        const unsigned short* Bb = BS[kt & 1];
        bf16x8 af[4][2], bf[4][2];

#pragma unroll
        for (int i = 0; i < 4; i++) {
            const int row = wm * 64 + i * 16 + l15;
#pragma unroll
            for (int kk = 0; kk < 2; kk++)
                af[i][kk] = *(const bf16x8*)&Ab[row * 64 + ((kk * 4 + quad) ^ (l15 & 7)) * 8];
        }
#pragma unroll
        for (int j = 0; j < 2; j++) {
            const int row = wn * 64 + j * 16 + l15;
#pragma unroll
            for (int kk = 0; kk < 2; kk++)
                bf[j][kk] = *(const bf16x8*)&Bb[row * 64 + ((kk * 4 + quad) ^ (l15 & 7)) * 8];
        }
        if (kt + 1 < ONKT) stageB(kt + 1);
        __builtin_amdgcn_s_barrier();
        __builtin_amdgcn_s_setprio(1);
#pragma unroll
        for (int i = 0; i < 4; i++)
#pragma unroll
            for (int j = 0; j < 2; j++) {
                acc[i][j] = mfma16(af[i][0], bf[j][0], acc[i][j]);
                acc[i][j] = mfma16(af[i][1], bf[j][1], acc[i][j]);
            }
        __builtin_amdgcn_s_setprio(0);
        __builtin_amdgcn_s_barrier();

#pragma unroll
        for (int j = 2; j < 4; j++) {
            const int row = wn * 64 + j * 16 + l15;
#pragma unroll
            for (int kk = 0; kk < 2; kk++)
                bf[j][kk] = *(const bf16x8*)&Bb[row * 64 + ((kk * 4 + quad) ^ (l15 & 7)) * 8];
        }
        if (kt + 2 < ONKT) stageA(kt + 2);
        __builtin_amdgcn_s_barrier();
        __builtin_amdgcn_s_setprio(1);
#pragma unroll
        for (int i = 0; i < 4; i++)
#pragma unroll
            for (int j = 2; j < 4; j++) {
                acc[i][j] = mfma16(af[i][0], bf[j][0], acc[i][j]);
                acc[i][j] = mfma16(af[i][1], bf[j][1], acc[i][j]);
            }
        __builtin_amdgcn_s_setprio(0);
    }

#pragma unroll
    for (int j = 0; j < 4; j++) {
        int col = n0 + wn * 64 + j * 16 + l15;
        float bv = bias[col];
#pragma unroll
        for (int i = 0; i < 4; i++) {
            int rowb = m0 + wm * 64 + i * 16 + quad * 4;
#pragma unroll
            for (int rr = 0; rr < 4; rr++)
                C[(size_t)(rowb + rr) * N + col] = acc[i][j][rr] + bv;
        }
    }
}

// ---------------- flash attention v8: ring-3 K/V, 1 barrier/tile, XCD swizzle -------
// Round-8: + XCD-chunked swizzle (512 blocks = 8 x 64 -> exactly 4 heads/XCD;
// K/V per XCD = 4MB = L2-exact, so the 16 blocks sharing a head's K/V hit L2).
#define TK 64
#define NTILE (SS / TK)   // 32
#define LDP 72            // padded LDS row stride (shorts)

__global__ __launch_bounds__(256, 2) void flash_attn(const unsigned short* __restrict__ Q,
                                                     const unsigned short* __restrict__ Kg,
                                                     const unsigned short* __restrict__ Vt,
                                                     unsigned short* __restrict__ ctx) {
    __shared__ alignas(16) unsigned short Ks[3][TK * LDP];
    __shared__ alignas(16) unsigned short Vs[3][TK * LDP];
    const int t = threadIdx.x;
    const int lane = t & 63, wave = t >> 6;
    const int quad = lane >> 4, l15 = lane & 15;
    // XCD swizzle: 512 blocks = 8 XCDs x 64 (bijective)
    const int swz = (blockIdx.x & 7) * 64 + (blockIdx.x >> 3);
    const int qg = swz & 15;    // q-group within head (16 groups of 128 q)
    const int bh = swz >> 4;    // 0..31
    const int h = bh & 15, b = bh >> 4;
    const int q0 = (qg * 4 + wave) * 32;   // wave owns q0..q0+31 (two 16-q tiles)

    const unsigned short* Qb = Q + (size_t)b * SS * DD + h * HD;
    const unsigned short* Kb = Kg + (size_t)b * SS * DD + h * HD;
    const unsigned short* Vb = Vt + ((size_t)b * DD + h * HD) * SS;  // rows: hd, stride S

    const int r0 = t >> 3, cs = t & 7;
    const unsigned short* gK = Kb + (size_t)r0 * DD + cs * 8;
    const unsigned short* gV = Vb + (size_t)r0 * SS + cs * 8;
    const int ldsoff0 = r0 * LDP + cs * 8;
    const int ldsoff1 = (r0 + 32) * LDP + cs * 8;

    bf16x8 qa[2][2];
#pragma unroll
    for (int qt = 0; qt < 2; qt++) {
        qa[qt][0] = *(const bf16x8*)(Qb + (size_t)(q0 + qt * 16 + l15) * DD + quad * 8);
        qa[qt][1] = *(const bf16x8*)(Qb + (size_t)(q0 + qt * 16 + l15) * DD + 32 + quad * 8);
    }

    float lrow[2] = {0.f, 0.f};
    f32x4 o[2][4];
#pragma unroll
    for (int qt = 0; qt < 2; qt++)
#pragma unroll
        for (int j = 0; j < 4; j++) o[qt][j] = (f32x4){0.f, 0.f, 0.f, 0.f};

    {
        uint4 kr0 = *(const uint4*)(gK);
        uint4 kr1 = *(const uint4*)(gK + (size_t)32 * DD);
        uint4 vr0 = *(const uint4*)(gV);
        uint4 vr1 = *(const uint4*)(gV + (size_t)32 * SS);
        *(uint4*)&Ks[0][ldsoff0] = kr0;
        *(uint4*)&Ks[0][ldsoff1] = kr1;
        *(uint4*)&Vs[0][ldsoff0] = vr0;
        *(uint4*)&Vs[0][ldsoff1] = vr1;
    }
    __syncthreads();

    int rb = 0;
    for (int tile = 0; tile < NTILE; ++tile) {
        uint4 kr0, kr1, vr0, vr1;
        if (tile + 1 < NTILE) {
            const unsigned short* gKn = gK + (size_t)(tile + 1) * TK * DD;
            const unsigned short* gVn = gV + (tile + 1) * TK;
            kr0 = *(const uint4*)(gKn);
            kr1 = *(const uint4*)(gKn + (size_t)32 * DD);
            vr0 = *(const uint4*)(gVn);
            vr1 = *(const uint4*)(gVn + (size_t)32 * SS);
        }
        const unsigned short* Ksb = Ks[rb];
        const unsigned short* Vsb = Vs[rb];
#pragma unroll
        for (int half = 0; half < 2; half++) {
            const int kb0 = half * 32;
            bf16x8 k0 = *(const bf16x8*)&Ksb[(kb0 + l15) * LDP + quad * 8];
            bf16x8 k1 = *(const bf16x8*)&Ksb[(kb0 + l15) * LDP + 32 + quad * 8];
            bf16x8 k2 = *(const bf16x8*)&Ksb[(kb0 + 16 + l15) * LDP + quad * 8];
            bf16x8 k3 = *(const bf16x8*)&Ksb[(kb0 + 16 + l15) * LDP + 32 + quad * 8];
            union { ushort4 s[2]; bf16x8 v; } af[4];
#pragma unroll
            for (int j = 0; j < 4; j++) {
                af[j].s[0] = *(const ushort4*)&Vsb[(j * 16 + l15) * LDP + kb0 + quad * 4];
                af[j].s[1] = *(const ushort4*)&Vsb[(j * 16 + l15) * LDP + kb0 + 16 + quad * 4];
            }
#pragma unroll
            for (int qt = 0; qt < 2; qt++) {
                f32x4 sc0 = (f32x4){0.f, 0.f, 0.f, 0.f};
                f32x4 sc1 = (f32x4){0.f, 0.f, 0.f, 0.f};
                sc0 = mfma16(k0, qa[qt][0], sc0);
                sc0 = mfma16(k1, qa[qt][1], sc0);
                sc1 = mfma16(k2, qa[qt][0], sc1);
                sc1 = mfma16(k3, qa[qt][1], sc1);

                float p[8];
#pragma unroll
                for (int rr = 0; rr < 4; rr++) {
                    p[rr]     = fast_exp2(sc0[rr]);
                    p[rr + 4] = fast_exp2(sc1[rr]);
                }
                lrow[qt] += (p[0] + p[1]) + (p[2] + p[3]) + (p[4] + p[5]) + (p[6] + p[7]);

                union { unsigned u[4]; bf16x8 v; } pf;
                pf.u[0] = pack2bf(p[0], p[1]);
                pf.u[1] = pack2bf(p[2], p[3]);
                pf.u[2] = pack2bf(p[4], p[5]);
                pf.u[3] = pack2bf(p[6], p[7]);

#pragma unroll
                for (int j = 0; j < 4; j++)
                    o[qt][j] = mfma16(af[j].v, pf.v, o[qt][j]);
            }
        }
        if (tile + 1 < NTILE) {
            int wb = rb + 1; if (wb == 3) wb = 0;
            *(uint4*)&Ks[wb][ldsoff0] = kr0;
            *(uint4*)&Ks[wb][ldsoff1] = kr1;
            *(uint4*)&Vs[wb][ldsoff0] = vr0;
            *(uint4*)&Vs[wb][ldsoff1] = vr1;
            __syncthreads();
            rb = wb;
        }
    }

#pragma unroll
    for (int qt = 0; qt < 2; qt++) {
        float l = lrow[qt];
        l += __shfl_xor(l, 16, 64);
        l += __shfl_xor(l, 32, 64);
        float linv = 1.0f / l;
        unsigned short* crow = ctx + ((size_t)b * SS + q0 + qt * 16 + l15) * DD + h * HD;
#pragma unroll
        for (int j = 0; j < 4; j++) {
            uint2 w;
            w.x = pack2bf(o[qt][j][0] * linv, o[qt][j][1] * linv);
            w.y = pack2bf(o[qt][j][2] * linv, o[qt][j][3] * linv);
            *(uint2*)(crow + j * 16 + quad * 4) = w;
        }
    }
}

extern "C" void kernel_launch(void* const* d_in, const int* in_sizes, int n_in,
                              void* d_out, int out_size, void* d_ws, size_t ws_size,
                              hipStream_t stream) {
    const float* query = (const float*)d_in[0];
    const float* key   = (const float*)d_in[1];
    const float* value = (const float*)d_in[2];
    const float* Wq = (const float*)d_in[3];
    const float* bq = (const float*)d_in[4];
    const float* Wk = (const float*)d_in[5];
    const float* bk = (const float*)d_in[6];
    const float* Wv = (const float*)d_in[7];
    const float* bv = (const float*)d_in[8];
    const float* Wo = (const float*)d_in[9];
    const float* bo = (const float*)d_in[10];
    float* out = (float*)d_out;

    char* ws = (char*)d_ws;
    const size_t WSZ = (size_t)DD * DD * 2;       // 2 MB per transposed weight
    const size_t XSZ = (size_t)MM * DD * 2;       // 8 MB per activation
    unsigned short* Wqt = (unsigned short*)(ws + 0 * WSZ);
    unsigned short* Wkt = (unsigned short*)(ws + 1 * WSZ);
    unsigned short* Wvt = (unsigned short*)(ws + 2 * WSZ);
    unsigned short* Wot = (unsigned short*)(ws + 3 * WSZ);
    unsigned short* Qp  = (unsigned short*)(ws + 4 * WSZ + 0 * XSZ);
    unsigned short* Kp  = (unsigned short*)(ws + 4 * WSZ + 1 * XSZ);
    unsigned short* Vtp = (unsigned short*)(ws + 4 * WSZ + 2 * XSZ);  // [B][D][S] direct
    unsigned short* ctx = (unsigned short*)(ws + 4 * WSZ + 3 * XSZ);

    // 1. prep: 4 weight transposes only (activation convert fused into gemm_qkv)
    PrepArgs pargs;
    pargs.wsrc[0] = Wq; pargs.wsrc[1] = Wk; pargs.wsrc[2] = Wv; pargs.wsrc[3] = Wo;
    pargs.wdst[0] = Wqt; pargs.wdst[1] = Wkt; pargs.wdst[2] = Wvt; pargs.wdst[3] = Wot;
    prep_inputs<<<dim3(32, 32, 4), 256, 0, stream>>>(pargs);

    // 2. Q/K/V projections: fp32 A read directly (reg-staged convert), XCD swizzle;
    //    z=2 writes V^T [B][D][S] directly (transpose fused). 1-D grid, 192 blocks.
    QKVArgs args;
    args.Af[0] = query; args.Af[1] = key; args.Af[2] = value;
    args.Bt[0] = Wqt; args.Bt[1] = Wkt; args.Bt[2] = Wvt;
    args.bias[0] = bq; args.bias[1] = bk; args.bias[2] = bv;
    args.C[0] = Qp; args.C[1] = Kp; args.C[2] = Vtp;
    gemm_qkv<<<(DD / 256) * (MM / 256) * 3, 512, 0, stream>>>(args);

    // 3. flash attention: 512 blocks, XCD-chunked (4 heads per XCD)
    flash_attn<<<BB * HH * 16, 256, 0, stream>>>(Qp, Kp, Vtp, ctx);

    // 4. output projection -> fp32: pipelined 128x128, 256 blocks, XCD swizzle
    gemm_out<<<(DD / 128) * (MM / 128), 256, 0, stream>>>(ctx, Wot, bo, out);
}

// Round 10
// 223.087 us; speedup vs baseline: 1.0198x; 1.0198x over previous
//
#include <hip/hip_runtime.h>
#include <hip/hip_bf16.h>

// Problem constants
#define BB 2
#define SS 2048
#define DD 1024
#define HH 16
#define HD 64
#define MM (BB*SS)   // 4096

typedef __attribute__((ext_vector_type(8))) short bf16x8;
typedef __attribute__((ext_vector_type(4))) float f32x4;
typedef __attribute__((ext_vector_type(16))) float f32x16;

static __device__ inline unsigned short f2bf(float x) {
    unsigned int u = __float_as_uint(x);
    unsigned int r = (u + 0x7fffu + ((u >> 16) & 1u)) >> 16;
    return (unsigned short)r;
}

// packed f32x2 -> bf16x2 via v_cvt_pk_bf16_f32 (RNE, bit-identical to f2bf)
static __device__ inline unsigned pack2bf(float lo, float hi) {
    union { __hip_bfloat162 h; unsigned u; } c;
    c.h = __float22bfloat162_rn(make_float2(lo, hi));
    return c.u;
}

static __device__ inline f32x4 mfma16(bf16x8 a, bf16x8 b, f32x4 c) {
    return __builtin_amdgcn_mfma_f32_16x16x32_bf16(a, b, c, 0, 0, 0);
}
static __device__ inline f32x16 mfma32(bf16x8 a, bf16x8 b, f32x16 c) {
    return __builtin_amdgcn_mfma_f32_32x32x16_bf16(a, b, c, 0, 0, 0);
}

// raw v_exp_f32 (2^x)
static __device__ inline float fast_exp2(float x) {
    return __builtin_amdgcn_exp2f(x);
}

// async global->LDS 16B per lane: LDS dest = wave-uniform base + lane*16
typedef __attribute__((address_space(3))) unsigned int lds_u32;
typedef const __attribute__((address_space(1))) unsigned int glb_u32;
static __device__ inline void async_ld16(const void* g, void* l) {
    __builtin_amdgcn_global_load_lds((glb_u32*)g, (lds_u32*)l, 16, 0, 0);
}

// half-swap across the lane<32 / lane>=32 split:
//   a' = {a.lo32lanes, b.lo32lanes}; b' = {a.hi32lanes, b.hi32lanes}
// shfl_xor formulation (safe codegen; the permlane builtin was the only
// unverifiable ingredient in the r9 container failure).
static __device__ inline void half_swap(unsigned& a, unsigned& b) {
    const int hi = (int)(threadIdx.x & 32);
    unsigned ax = (unsigned)__shfl_xor((int)a, 32, 64);
    unsigned bx = (unsigned)__shfl_xor((int)b, 32, 64);
    unsigned na = hi ? bx : a;
    unsigned nb = hi ? b : ax;
    a = na; b = nb;
}

// ---------------- prep (weights only): transpose+convert [R][C]fp32 -> [C][R]bf16
struct PrepArgs {
    const float* wsrc[4];
    unsigned short* wdst[4];
};
__global__ __launch_bounds__(256) void prep_inputs(PrepArgs args) {
    __shared__ float tile[32][33];
    const int z = blockIdx.z;
    const int t = threadIdx.x;
    const float* in = args.wsrc[z];
    unsigned short* out = args.wdst[z];
    const int c0 = blockIdx.x * 32, r0 = blockIdx.y * 32;
    {
        const int xf = (t & 7) * 4, yf = t >> 3;     // load float4 per thread
        float4 v = *(const float4*)(in + (size_t)(r0 + yf) * DD + c0 + xf);
        tile[yf][xf + 0] = v.x;
        tile[yf][xf + 1] = v.y;
        tile[yf][xf + 2] = v.z;
        tile[yf][xf + 3] = v.w;
    }
    __syncthreads();
    {
        const int x8 = t & 7, y8 = t >> 3;           // one uint2 (4 bf16) per thread
        uint2 w;
        w.x = pack2bf(tile[x8 * 4 + 0][y8], tile[x8 * 4 + 1][y8]);
        w.y = pack2bf(tile[x8 * 4 + 2][y8], tile[x8 * 4 + 3][y8]);
        *(uint2*)(out + (size_t)(c0 + y8) * DD + r0 + x8 * 4) = w;
    }
}

struct QKVArgs {
    const float* Af[3];           // raw fp32 activations (query/key/value)
    const unsigned short* Bt[3];
    const float* bias[3];
    unsigned short* C[3];
};

// Q scale folds 1/sqrt(HD) AND log2(e) so flash can use exp2 directly.
#define QSCALE 0.1803368801111204f

// ---------------- QKV GEMM: 256x256, BK=64, 2-buf, fused fp32->bf16 A-staging ------
// (r8 version, unchanged: XCD-chunked bijective swizzle, FETCH-verified)
#define NKT 16   // K / 64

__global__ __launch_bounds__(512, 2) void gemm_qkv(QKVArgs args) {
    __shared__ alignas(16) unsigned short AS[2][256 * 64];
    __shared__ alignas(16) unsigned short BS[2][256 * 64];
    // ---- XCD swizzle: 192 blocks = 8 XCDs x 24-tile chunks (bijective: 192%8==0)
    const int lin = blockIdx.x;
    const int swz = (lin & 7) * 24 + (lin >> 3);
    const int z  = swz >> 6;            // 0..2
    const int by = (swz >> 2) & 15;     // 0..15
    const int bx = swz & 3;             // 0..3
    const float scale = (z == 0) ? QSCALE : 1.0f;
    const float* __restrict__ Af = args.Af[z];
    const unsigned short* __restrict__ Bt = args.Bt[z];
    const float* __restrict__ bias = args.bias[z];
    unsigned short* __restrict__ C = args.C[z];
    const int K = DD, N = DD;
    const int t = threadIdx.x;
    const int lane = t & 63, wave = t >> 6;
    const int quad = lane >> 4, l15 = lane & 15;
    const int wm = wave & 1, wn = wave >> 1;    // 2 M-waves x 4 N-waves
    const int m0 = by * 256, n0 = bx * 256;

    const int srow = t >> 3;                     // 0..63
    const int cslot = (t & 7) ^ (srow & 7);
    const unsigned short* gB = Bt + (size_t)(n0 + srow) * K + cslot * 8;
    const int dstoff = srow * 64 + (t & 7) * 8;  // bytes = t*16 within group

    auto stageB = [&](int tl, int h) {           // h: 0 = rows 0..127, 1 = 128..255
        unsigned short* d = &BS[tl & 1][h * 128 * 64 + dstoff];
        const unsigned short* s = gB + (size_t)(h * 128) * K + (size_t)tl * 64;
        async_ld16(s, d);
        async_ld16(s + (size_t)64 * K, d + 64 * 64);
    };

    const int ar_ = t >> 3, as_ = t & 7;
    const int sw = as_ ^ (ar_ & 7);
    const float* gA0 = Af + (size_t)(m0 + 0 * 64 + ar_) * K + sw * 8;
    const float* gA1 = Af + (size_t)(m0 + 1 * 64 + ar_) * K + sw * 8;
    const float* gA2 = Af + (size_t)(m0 + 2 * 64 + ar_) * K + sw * 8;
    const float* gA3 = Af + (size_t)(m0 + 3 * 64 + ar_) * K + sw * 8;

    float4 fA0[8], fA1[8];
#define ISSUE_A(buf_, tl_)                                                    \
    {                                                                         \
        const size_t ko_ = (size_t)(tl_) * 64;                                \
        buf_[0] = *(const float4*)(gA0 + ko_);                                \
        buf_[1] = *(const float4*)(gA0 + ko_ + 4);                            \
        buf_[2] = *(const float4*)(gA1 + ko_);                                \
        buf_[3] = *(const float4*)(gA1 + ko_ + 4);                            \
        buf_[4] = *(const float4*)(gA2 + ko_);                                \
        buf_[5] = *(const float4*)(gA2 + ko_ + 4);                            \
        buf_[6] = *(const float4*)(gA3 + ko_);                                \
        buf_[7] = *(const float4*)(gA3 + ko_ + 4);                            \
    }
#define CVT_WRITE_A(buf_, tl_)                                                \
    {                                                                         \
        _Pragma("unroll")                                                     \
        for (int h = 0; h < 4; h++) {                                         \
            uint4 w_;                                                         \
            w_.x = pack2bf(buf_[h * 2].x, buf_[h * 2].y);                     \
            w_.y = pack2bf(buf_[h * 2].z, buf_[h * 2].w);                     \
            w_.z = pack2bf(buf_[h * 2 + 1].x, buf_[h * 2 + 1].y);             \
            w_.w = pack2bf(buf_[h * 2 + 1].z, buf_[h * 2 + 1].w);             \
            *(uint4*)&AS[(tl_) & 1][(h * 64 + ar_) * 64 + as_ * 8] = w_;      \
        }                                                                     \
    }

    ISSUE_A(fA0, 0);
    stageB(0, 0); stageB(0, 1);
    ISSUE_A(fA1, 1);
    asm volatile("s_waitcnt vmcnt(8)" ::: "memory");   // a0 + B0 done, a1 in flight
    CVT_WRITE_A(fA0, 0);
    asm volatile("s_waitcnt lgkmcnt(0)" ::: "memory");
    __builtin_amdgcn_s_barrier();

    f32x4 acc[8][4];
#pragma unroll
    for (int i = 0; i < 8; i++)
#pragma unroll
        for (int j = 0; j < 4; j++) acc[i][j] = (f32x4){0.f, 0.f, 0.f, 0.f};

#pragma unroll 2
    for (int kt = 0; kt < NKT; ++kt) {
        if (kt > 0) {
            if (kt < NKT - 1) asm volatile("s_waitcnt vmcnt(8) lgkmcnt(0)" ::: "memory");
            else              asm volatile("s_waitcnt vmcnt(0) lgkmcnt(0)" ::: "memory");
            __builtin_amdgcn_s_barrier();
        }

        const unsigned short* Ab = AS[kt & 1];
        const unsigned short* Bb = BS[kt & 1];
        bf16x8 af[4][2], bf[4][2];

        // ---- P0
#pragma unroll
        for (int i = 0; i < 4; i++) {
            const int row = wm * 128 + i * 16 + l15;
#pragma unroll
            for (int kk = 0; kk < 2; kk++)
                af[i][kk] = *(const bf16x8*)&Ab[row * 64 + ((kk * 4 + quad) ^ (l15 & 7)) * 8];
        }
#pragma unroll
        for (int j = 0; j < 2; j++) {
            const int row = wn * 64 + j * 16 + l15;
#pragma unroll
            for (int kk = 0; kk < 2; kk++)
                bf[j][kk] = *(const bf16x8*)&Bb[row * 64 + ((kk * 4 + quad) ^ (l15 & 7)) * 8];
        }
        if (kt + 1 < NKT) { stageB(kt + 1, 0); stageB(kt + 1, 1); }
        __builtin_amdgcn_s_barrier();
        __builtin_amdgcn_s_setprio(1);
#pragma unroll
        for (int i = 0; i < 4; i++)
#pragma unroll
            for (int j = 0; j < 2; j++) {
                acc[i][j] = mfma16(af[i][0], bf[j][0], acc[i][j]);
                acc[i][j] = mfma16(af[i][1], bf[j][1], acc[i][j]);
            }
        __builtin_amdgcn_s_setprio(0);
        __builtin_amdgcn_s_barrier();

        // ---- P1
#pragma unroll
        for (int j = 2; j < 4; j++) {
            const int row = wn * 64 + j * 16 + l15;
#pragma unroll
            for (int kk = 0; kk < 2; kk++)
                bf[j][kk] = *(const bf16x8*)&Bb[row * 64 + ((kk * 4 + quad) ^ (l15 & 7)) * 8];
        }
        __builtin_amdgcn_s_barrier();
        __builtin_amdgcn_s_setprio(1);
#pragma unroll
        for (int i = 0; i < 4; i++)
#pragma unroll
            for (int j = 2; j < 4; j++) {
                acc[i][j] = mfma16(af[i][0], bf[j][0], acc[i][j]);
                acc[i][j] = mfma16(af[i][1], bf[j][1], acc[i][j]);
            }
        __builtin_amdgcn_s_setprio(0);
        __builtin_amdgcn_s_barrier();

        // ---- P2
#pragma unroll
        for (int i = 0; i < 4; i++) {
            const int row = wm * 128 + 64 + i * 16 + l15;
#pragma unroll
            for (int kk = 0; kk < 2; kk++)
                af[i][kk] = *(const bf16x8*)&Ab[row * 64 + ((kk * 4 + quad) ^ (l15 & 7)) * 8];
        }
        __builtin_amdgcn_s_barrier();
        __builtin_amdgcn_s_setprio(1);
#pragma unroll
        for (int i = 0; i < 4; i++)
#pragma unroll
            for (int j = 0; j < 2; j++) {
                acc[4 + i][j] = mfma16(af[i][0], bf[j][0], acc[4 + i][j]);
                acc[4 + i][j] = mfma16(af[i][1], bf[j][1], acc[4 + i][j]);
            }
        __builtin_amdgcn_s_setprio(0);
        __builtin_amdgcn_s_barrier();

        // ---- P3
        if (kt + 1 < NKT) {
            CVT_WRITE_A(fA1, kt + 1);
            if (kt + 2 < NKT) ISSUE_A(fA1, kt + 2);
        }
        __builtin_amdgcn_s_barrier();
        __builtin_amdgcn_s_setprio(1);
#pragma unroll
        for (int i = 0; i < 4; i++)
#pragma unroll
            for (int j = 2; j < 4; j++) {
                acc[4 + i][j] = mfma16(af[i][0], bf[j][0], acc[4 + i][j]);
                acc[4 + i][j] = mfma16(af[i][1], bf[j][1], acc[4 + i][j]);
            }
        __builtin_amdgcn_s_setprio(0);
    }

    if (z == 2) {
#pragma unroll
        for (int j = 0; j < 4; j++) {
            int col = n0 + wn * 64 + j * 16 + l15;
            float bv = bias[col];
#pragma unroll
            for (int i = 0; i < 8; i++) {
                int rowb = m0 + wm * 128 + i * 16 + quad * 4;
                int b = rowb >> 11, s = rowb & (SS - 1);
                uint2 w;
                w.x = pack2bf(acc[i][j][0] + bv, acc[i][j][1] + bv);
                w.y = pack2bf(acc[i][j][2] + bv, acc[i][j][3] + bv);
                *(uint2*)(C + (size_t)b * DD * SS + (size_t)col * SS + s) = w;
            }
        }
    } else {
#pragma unroll
        for (int j = 0; j < 4; j++) {
            int col = n0 + wn * 64 + j * 16 + l15;
            float bv = bias[col];
#pragma unroll
            for (int i = 0; i < 8; i++) {
                int rowb = m0 + wm * 128 + i * 16 + quad * 4;
#pragma unroll
                for (int rr = 0; rr < 4; rr++) {
                    float v = (acc[i][j][rr] + bv) * scale;
                    C[(size_t)(rowb + rr) * N + col] = f2bf(v);
                }
            }
        }
    }
#undef ISSUE_A
#undef CVT_WRITE_A
}

// ---------------- output projection: pipelined 128x128, BK=64, 2-buf, XCD swizzle ---
#define ONKT 16   // K / 64

__global__ __launch_bounds__(256, 2) void gemm_out(const unsigned short* __restrict__ A,
                                                   const unsigned short* __restrict__ Bt,
                                                   const float* __restrict__ bias,
                                                   float* __restrict__ C) {
    __shared__ alignas(16) unsigned short AS[2][128 * 64];
    __shared__ alignas(16) unsigned short BS[2][128 * 64];
    const int t = threadIdx.x;
    const int lane = t & 63, wave = t >> 6;
    const int quad = lane >> 4, l15 = lane & 15;
    const int wm = wave & 1, wn = wave >> 1;    // 2 M-waves x 2 N-waves
    const int lin = blockIdx.x;
    const int swz = (lin & 7) * 32 + (lin >> 3);
    const int bx = swz & 7, by = swz >> 3;
    const int m0 = by * 128, n0 = bx * 128;
    const int K = DD, N = DD;

    const int srow = t >> 3;                     // 0..31
    const int cslot = (t & 7) ^ (srow & 7);
    const unsigned short* gA = A + (size_t)(m0 + srow) * K + cslot * 8;
    const unsigned short* gB = Bt + (size_t)(n0 + srow) * K + cslot * 8;
    const int dstoff = srow * 64 + (t & 7) * 8;

    auto stageA = [&](int tl) {
        unsigned short* d = &AS[tl & 1][dstoff];
        const unsigned short* s = gA + (size_t)tl * 64;
#pragma unroll
        for (int r = 0; r < 4; r++)
            async_ld16(s + (size_t)(r * 32) * K, d + r * 32 * 64);
    };
    auto stageB = [&](int tl) {
        unsigned short* d = &BS[tl & 1][dstoff];
        const unsigned short* s = gB + (size_t)tl * 64;
#pragma unroll
        for (int r = 0; r < 4; r++)
            async_ld16(s + (size_t)(r * 32) * K, d + r * 32 * 64);
    };

    stageA(0); stageB(0); stageA(1);

    f32x4 acc[4][4];
#pragma unroll
    for (int i = 0; i < 4; i++)
#pragma unroll
        for (int j = 0; j < 4; j++) acc[i][j] = (f32x4){0.f, 0.f, 0.f, 0.f};

#pragma unroll 2
    for (int kt = 0; kt < ONKT; ++kt) {
        if (kt < ONKT - 1) asm volatile("s_waitcnt vmcnt(4)" ::: "memory");
        else               asm volatile("s_waitcnt vmcnt(0)" ::: "memory");
        __builtin_amdgcn_s_barrier();

        const unsigned short* Ab = AS[kt & 1];
        const unsigned short* Bb = BS[kt & 1];
        bf16x8 af[4][2], bf[4][2];

#pragma unroll
        for (int i = 0; i < 4; i++) {
            const int row = wm * 64 + i * 16 + l15;
#pragma unroll
            for (int kk = 0; kk < 2; kk++)
                af[i][kk] = *(const bf16x8*)&Ab[row * 64 + ((kk * 4 + quad) ^ (l15 & 7)) * 8];
        }
#pragma unroll
        for (int j = 0; j < 2; j++) {
            const int row = wn * 64 + j * 16 + l15;
#pragma unroll
            for (int kk = 0; kk < 2; kk++)
                bf[j][kk] = *(const bf16x8*)&Bb[row * 64 + ((kk * 4 + quad) ^ (l15 & 7)) * 8];
        }
        if (kt + 1 < ONKT) stageB(kt + 1);
        __builtin_amdgcn_s_barrier();
        __builtin_amdgcn_s_setprio(1);
#pragma unroll
        for (int i = 0; i < 4; i++)
#pragma unroll
            for (int j = 0; j < 2; j++) {
                acc[i][j] = mfma16(af[i][0], bf[j][0], acc[i][j]);
                acc[i][j] = mfma16(af[i][1], bf[j][1], acc[i][j]);
            }
        __builtin_amdgcn_s_setprio(0);
        __builtin_amdgcn_s_barrier();

#pragma unroll
        for (int j = 2; j < 4; j++) {
            const int row = wn * 64 + j * 16 + l15;
#pragma unroll
            for (int kk = 0; kk < 2; kk++)
                bf[j][kk] = *(const bf16x8*)&Bb[row * 64 + ((kk * 4 + quad) ^ (l15 & 7)) * 8];
        }
        if (kt + 2 < ONKT) stageA(kt + 2);
        __builtin_amdgcn_s_barrier();
        __builtin_amdgcn_s_setprio(1);
#pragma unroll
        for (int i = 0; i < 4; i++)
#pragma unroll
            for (int j = 2; j < 4; j++) {
                acc[i][j] = mfma16(af[i][0], bf[j][0], acc[i][j]);
                acc[i][j] = mfma16(af[i][1], bf[j][1], acc[i][j]);
            }
        __builtin_amdgcn_s_setprio(0);
    }

#pragma unroll
    for (int j = 0; j < 4; j++) {
        int col = n0 + wn * 64 + j * 16 + l15;
        float bv = bias[col];
#pragma unroll
        for (int i = 0; i < 4; i++) {
            int rowb = m0 + wm * 64 + i * 16 + quad * 4;
#pragma unroll
            for (int rr = 0; rr < 4; rr++)
                C[(size_t)(rowb + rr) * N + col] = acc[i][j][rr] + bv;
        }
    }
}

// ---------------- flash attention v10: 32x32 MFMA + in-register softmax -------------
#define TK 64
#define NTILE (SS / TK)   // 32
#define LDP 72            // padded LDS row stride (shorts)

__global__ __launch_bounds__(256, 2) void flash_attn(const unsigned short* __restrict__ Q,
                                                     const unsigned short* __restrict__ Kg,
                                                     const unsigned short* __restrict__ Vt,
                                                     unsigned short* __restrict__ ctx) {
    __shared__ alignas(16) unsigned short Ks[3][TK * LDP];
    __shared__ alignas(16) unsigned short Vs[3][TK * LDP];
    const int t = threadIdx.x;
    const int lane = t & 63, wave = t >> 6;
    const int l31 = lane & 31, ch = lane >> 5;
    // XCD swizzle: 512 blocks = 8 XCDs x 64 (bijective)
    const int swz = (blockIdx.x & 7) * 64 + (blockIdx.x >> 3);
    const int qg = swz & 15;    // q-group within head (16 groups of 128 q)
    const int bh = swz >> 4;    // 0..31
    const int h = bh & 15, b = bh >> 4;
    const int q0 = (qg * 4 + wave) * 32;   // wave owns q0..q0+31

    const unsigned short* Qb = Q + (size_t)b * SS * DD + h * HD;
    const unsigned short* Kb = Kg + (size_t)b * SS * DD + h * HD;
    const unsigned short* Vb = Vt + ((size_t)b * DD + h * HD) * SS;  // rows: hd, stride S

    const int r0 = t >> 3, cs = t & 7;
    const unsigned short* gK = Kb + (size_t)r0 * DD + cs * 8;
    const unsigned short* gV = Vb + (size_t)r0 * SS + cs * 8;
    const int ldsoff0 = r0 * LDP + cs * 8;
    const int ldsoff1 = (r0 + 32) * LDP + cs * 8;

    // Q fragments: lane holds Q[q0+l31][d4*16 + ch*8 .. +8]
    bf16x8 qa[4];
#pragma unroll
    for (int d4 = 0; d4 < 4; d4++)
        qa[d4] = *(const bf16x8*)(Qb + (size_t)(q0 + l31) * DD + d4 * 16 + ch * 8);

    float lrow = 0.f;
    f32x16 o0, o1;
#pragma unroll
    for (int i = 0; i < 16; i++) { o0[i] = 0.f; o1[i] = 0.f; }

    {
        uint4 kr0 = *(const uint4*)(gK);
        uint4 kr1 = *(const uint4*)(gK + (size_t)32 * DD);
        uint4 vr0 = *(const uint4*)(gV);
        uint4 vr1 = *(const uint4*)(gV + (size_t)32 * SS);
        *(uint4*)&Ks[0][ldsoff0] = kr0;
        *(uint4*)&Ks[0][ldsoff1] = kr1;
        *(uint4*)&Vs[0][ldsoff0] = vr0;
        *(uint4*)&Vs[0][ldsoff1] = vr1;
    }
    __syncthreads();

    int rb = 0;
    for (int tile = 0; tile < NTILE; ++tile) {
        uint4 kr0, kr1, vr0, vr1;
        if (tile + 1 < NTILE) {
            const unsigned short* gKn = gK + (size_t)(tile + 1) * TK * DD;
            const unsigned short* gVn = gV + (tile + 1) * TK;
            kr0 = *(const uint4*)(gKn);
            kr1 = *(const uint4*)(gKn + (size_t)32 * DD);
            vr0 = *(const uint4*)(gVn);
            vr1 = *(const uint4*)(gVn + (size_t)32 * SS);
        }
        const unsigned short* Ksb = Ks[rb];
        const unsigned short* Vsb = Vs[rb];

#pragma unroll
        for (int st = 0; st < 2; st++) {           // two 32-k subtiles
            bf16x8 ka[4];
#pragma unroll
            for (int d4 = 0; d4 < 4; d4++)
                ka[d4] = *(const bf16x8*)&Ksb[(st * 32 + l31) * LDP + d4 * 16 + ch * 8];
            f32x16 sc;
#pragma unroll
            for (int i = 0; i < 16; i++) sc[i] = 0.f;
            __builtin_amdgcn_s_setprio(1);
            sc = mfma32(ka[0], qa[0], sc);
            sc = mfma32(ka[1], qa[1], sc);
            sc = mfma32(ka[2], qa[2], sc);
            sc = mfma32(ka[3], qa[3], sc);
            __builtin_amdgcn_s_setprio(0);

            float p[16];
#pragma unroll
            for (int i = 0; i < 16; i++) p[i] = fast_exp2(sc[i]);
            lrow += (((p[0] + p[1]) + (p[2] + p[3])) + ((p[4] + p[5]) + (p[6] + p[7])))
                  + (((p[8] + p[9]) + (p[10] + p[11])) + ((p[12] + p[13]) + (p[14] + p[15])));

            // build PV B-frags: frag0 = subtile s 0..15, frag1 = s 16..31
            unsigned cA0 = pack2bf(p[0], p[1]),   cC0 = pack2bf(p[2], p[3]);
            unsigned cB0 = pack2bf(p[4], p[5]),   cD0 = pack2bf(p[6], p[7]);
            half_swap(cA0, cB0);
            half_swap(cC0, cD0);
            union { unsigned u[4]; bf16x8 v; } f0;
            f0.u[0] = cA0; f0.u[1] = cC0; f0.u[2] = cB0; f0.u[3] = cD0;

            unsigned cA1 = pack2bf(p[8], p[9]),   cC1 = pack2bf(p[10], p[11]);
            unsigned cB1 = pack2bf(p[12], p[13]), cD1 = pack2bf(p[14], p[15]);
            half_swap(cA1, cB1);
            half_swap(cC1, cD1);
            union { unsigned u[4]; bf16x8 v; } f1;
            f1.u[0] = cA1; f1.u[1] = cC1; f1.u[2] = cB1; f1.u[3] = cD1;

            // PV: A = V^T[hd][s-slice], B = P-frag
            bf16x8 v00 = *(const bf16x8*)&Vsb[(0 * 32 + l31) * LDP + st * 32 + ch * 8];
            bf16x8 v01 = *(const bf16x8*)&Vsb[(0 * 32 + l31) * LDP + st * 32 + 16 + ch * 8];
            bf16x8 v10 = *(const bf16x8*)&Vsb[(1 * 32 + l31) * LDP + st * 32 + ch * 8];
            bf16x8 v11 = *(const bf16x8*)&Vsb[(1 * 32 + l31) * LDP + st * 32 + 16 + ch * 8];
            __builtin_amdgcn_s_setprio(1);
            o0 = mfma32(v00, f0.v, o0);
            o0 = mfma32(v01, f1.v, o0);
            o1 = mfma32(v10, f0.v, o1);
            o1 = mfma32(v11, f1.v, o1);
            __builtin_amdgcn_s_setprio(0);
        }

        if (tile + 1 < NTILE) {
            int wb = rb + 1; if (wb == 3) wb = 0;
            *(uint4*)&Ks[wb][ldsoff0] = kr0;
            *(uint4*)&Ks[wb][ldsoff1] = kr1;
            *(uint4*)&Vs[wb][ldsoff0] = vr0;
            *(uint4*)&Vs[wb][ldsoff1] = vr1;
            __syncthreads();
            rb = wb;
        }
    }

    // reduce l across the two k-halves (lanes l and l+32 hold same q)
    lrow += __shfl_xor(lrow, 32, 64);
    const float linv = 1.0f / lrow;
    unsigned short* crow = ctx + ((size_t)b * SS + q0 + l31) * DD + h * HD;
#pragma unroll
    for (int q4 = 0; q4 < 4; q4++) {
        {
            const int hd0 = 8 * q4 + 4 * ch;
            uint2 w;
            w.x = pack2bf(o0[q4 * 4 + 0] * linv, o0[q4 * 4 + 1] * linv);
            w.y = pack2bf(o0[q4 * 4 + 2] * linv, o0[q4 * 4 + 3] * linv);
            *(uint2*)(crow + hd0) = w;
        }
        {
            const int hd0 = 8 * q4 + 4 * ch + 32;
            uint2 w;
            w.x = pack2bf(o1[q4 * 4 + 0] * linv, o1[q4 * 4 + 1] * linv);
            w.y = pack2bf(o1[q4 * 4 + 2] * linv, o1[q4 * 4 + 3] * linv);
            *(uint2*)(crow + hd0) = w;
        }
    }
}

extern "C" void kernel_launch(void* const* d_in, const int* in_sizes, int n_in,
                              void* d_out, int out_size, void* d_ws, size_t ws_size,
                              hipStream_t stream) {
    const float* query = (const float*)d_in[0];
    const float* key   = (const float*)d_in[1];
    const float* value = (const float*)d_in[2];
    const float* Wq = (const float*)d_in[3];
    const float* bq = (const float*)d_in[4];
    const float* Wk = (const float*)d_in[5];
    const float* bk = (const float*)d_in[6];
    const float* Wv = (const float*)d_in[7];
    const float* bv = (const float*)d_in[8];
    const float* Wo = (const float*)d_in[9];
    const float* bo = (const float*)d_in[10];
    float* out = (float*)d_out;

    char* ws = (char*)d_ws;
    const size_t WSZ = (size_t)DD * DD * 2;       // 2 MB per transposed weight
    const size_t XSZ = (size_t)MM * DD * 2;       // 8 MB per activation
    unsigned short* Wqt = (unsigned short*)(ws + 0 * WSZ);
    unsigned short* Wkt = (unsigned short*)(ws + 1 * WSZ);
    unsigned short* Wvt = (unsigned short*)(ws + 2 * WSZ);
    unsigned short* Wot = (unsigned short*)(ws + 3 * WSZ);
    unsigned short* Qp  = (unsigned short*)(ws + 4 * WSZ + 0 * XSZ);
    unsigned short* Kp  = (unsigned short*)(ws + 4 * WSZ + 1 * XSZ);
    unsigned short* Vtp = (unsigned short*)(ws + 4 * WSZ + 2 * XSZ);  // [B][D][S] direct
    unsigned short* ctx = (unsigned short*)(ws + 4 * WSZ + 3 * XSZ);

    // 1. prep: 4 weight transposes only
    PrepArgs pargs;
    pargs.wsrc[0] = Wq; pargs.wsrc[1] = Wk; pargs.wsrc[2] = Wv; pargs.wsrc[3] = Wo;
    pargs.wdst[0] = Wqt; pargs.wdst[1] = Wkt; pargs.wdst[2] = Wvt; pargs.wdst[3] = Wot;
    prep_inputs<<<dim3(32, 32, 4), 256, 0, stream>>>(pargs);

    // 2. Q/K/V projections (r8 version)
    QKVArgs args;
    args.Af[0] = query; args.Af[1] = key; args.Af[2] = value;
    args.Bt[0] = Wqt; args.Bt[1] = Wkt; args.Bt[2] = Wvt;
    args.bias[0] = bq; args.bias[1] = bk; args.bias[2] = bv;
    args.C[0] = Qp; args.C[1] = Kp; args.C[2] = Vtp;
    gemm_qkv<<<(DD / 256) * (MM / 256) * 3, 512, 0, stream>>>(args);

    // 3. flash attention v10 (32x32 MFMA core), 512 blocks, XCD-chunked
    flash_attn<<<BB * HH * 16, 256, 0, stream>>>(Qp, Kp, Vtp, ctx);

    // 4. output projection -> fp32 (r8 version)
    gemm_out<<<(DD / 128) * (MM / 128), 256, 0, stream>>>(ctx, Wot, bo, out);
}